// Round 1
// baseline (17.970 us; speedup 1.0000x reference)
//
#include <hip/hip_runtime.h>

#define NBEST 50
#define SEGS_PER_BLOCK 4   // 4 waves of 64 per block, one segment per wave
#define MARGIN 0.1f

// Kernel 1: one wavefront per segment.
// lanes 0..49 gather ranked scores r_j = scores[seg, werRank[seg,j]] into an
// LDS row; each lane j computes sum_{k>j} relu(margin-(r_j-r_k)) / (N-1-j);
// wave shuffle-reduce; block writes one partial to d_ws.
__global__ void margin_partial_kernel(const float* __restrict__ scores,
                                      const int* __restrict__ werRank,
                                      float* __restrict__ partials,
                                      int B) {
    const int wave = threadIdx.x >> 6;   // 0..3
    const int lane = threadIdx.x & 63;   // 0..63
    const int seg  = blockIdx.x * SEGS_PER_BLOCK + wave;

    __shared__ float r[SEGS_PER_BLOCK][64];
    __shared__ float wsum[SEGS_PER_BLOCK];

    float rj = 0.0f;
    if (seg < B && lane < NBEST) {
        const int idx = werRank[seg * NBEST + lane];   // permutation index
        rj = scores[seg * NBEST + idx];                // gather within 200B segment
    }
    r[wave][lane] = rj;          // lanes 50..63 write 0 (read-safe)
    __syncthreads();

    // Uniform 50-iteration loop: all lanes read the same LDS address each
    // iteration (broadcast, conflict-free); predicate selects k > lane.
    float acc = 0.0f;
    #pragma unroll
    for (int k = 0; k < NBEST; ++k) {
        float d = MARGIN - (rj - r[wave][k]);
        d = fmaxf(d, 0.0f);
        acc += (k > lane) ? d : 0.0f;
    }
    // reduction='mean' over the (N-1-j) negatives for rank j; last rank has none.
    float val = (seg < B && lane < NBEST - 1)
                    ? acc / (float)(NBEST - 1 - lane)
                    : 0.0f;

    // 64-lane butterfly reduction
    #pragma unroll
    for (int off = 32; off >= 1; off >>= 1)
        val += __shfl_xor(val, off, 64);

    if (lane == 0) wsum[wave] = val;
    __syncthreads();

    if (threadIdx.x == 0) {
        float s = 0.0f;
        #pragma unroll
        for (int w = 0; w < SEGS_PER_BLOCK; ++w) s += wsum[w];
        partials[blockIdx.x] = s;
    }
}

// Kernel 2: deterministic fixed-order reduction of the per-block partials.
__global__ void margin_reduce_kernel(const float* __restrict__ partials,
                                     int n, float* __restrict__ out) {
    __shared__ float sm[256];
    float s = 0.0f;
    for (int i = threadIdx.x; i < n; i += 256) s += partials[i];
    sm[threadIdx.x] = s;
    __syncthreads();
    #pragma unroll
    for (int off = 128; off >= 1; off >>= 1) {
        if (threadIdx.x < off) sm[threadIdx.x] += sm[threadIdx.x + off];
        __syncthreads();
    }
    if (threadIdx.x == 0) out[0] = sm[0];
}

extern "C" void kernel_launch(void* const* d_in, const int* in_sizes, int n_in,
                              void* d_out, int out_size, void* d_ws, size_t ws_size,
                              hipStream_t stream) {
    const float* scores  = (const float*)d_in[0];
    const int*   werRank = (const int*)d_in[1];
    float*       out     = (float*)d_out;
    float*       partials = (float*)d_ws;   // grid1 floats (16 KB) << ws_size

    const int B = in_sizes[0] / NBEST;      // 16384
    const int grid1 = (B + SEGS_PER_BLOCK - 1) / SEGS_PER_BLOCK;  // 4096

    margin_partial_kernel<<<grid1, SEGS_PER_BLOCK * 64, 0, stream>>>(
        scores, werRank, partials, B);
    margin_reduce_kernel<<<1, 256, 0, stream>>>(partials, grid1, out);
}